// Round 1
// baseline (2994.369 us; speedup 1.0000x reference)
//
#include <hip/hip_runtime.h>

// GraphSAGE 2-layer, fp32. N=50000, E=800000, D_IN=128, D_H=256, D_OUT=128.
//
// Pipeline (all on `stream`):
//   1. zero agg1+deg+inv (contig) and agg2
//   2. scatter1: agg1[dst] += x[src] (128 f), deg[dst] += 1
//   3. mean_scale: agg1 *= 1/max(deg,1) (in place), write inv_deg
//   4. gemm EPI=0: h = relu(mean1@W1l.T + x@W1r.T + b1l)        [N,256]
//   5. gemm EPI=1: t = h@W2l.T                                   [N,128] (reuses agg1 buf)
//   6. scatter2: agg2[dst] += t[src]
//   7. gemm EPI=2: out = inv_deg*agg2 + h@W2r.T + b2l            [N,128]
//
// Layer-2 trick: mean(h[src])@W2l.T == mean((h@W2l.T)[src]) -> scatter 128
// floats/edge instead of 256.

__global__ void zero4_kernel(float4* __restrict__ p, int n4) {
  int i = blockIdx.x * blockDim.x + threadIdx.x;
  if (i < n4) p[i] = make_float4(0.f, 0.f, 0.f, 0.f);
}

// 32 lanes per edge, float4 per lane (128 floats/edge).
__global__ void scatter_kernel(const float* __restrict__ feat,
                               const int* __restrict__ src,
                               const int* __restrict__ dst,
                               float* __restrict__ agg,
                               float* __restrict__ deg,
                               int E) {
  int tid = blockIdx.x * blockDim.x + threadIdx.x;
  int estride = (gridDim.x * blockDim.x) >> 5;
  int lane = tid & 31;
  for (int e = tid >> 5; e < E; e += estride) {
    int s = src[e];
    int d = dst[e];
    float4 v = ((const float4*)(feat + (size_t)s * 128))[lane];
    float* a = agg + (size_t)d * 128 + lane * 4;
    unsafeAtomicAdd(a + 0, v.x);
    unsafeAtomicAdd(a + 1, v.y);
    unsafeAtomicAdd(a + 2, v.z);
    unsafeAtomicAdd(a + 3, v.w);
    if (deg != nullptr && lane == 0) unsafeAtomicAdd(deg + d, 1.0f);
  }
}

// agg *= 1/max(deg,1) elementwise (float4 granularity); also emit inv_deg[n].
__global__ void mean_scale_kernel(float* __restrict__ agg,
                                  const float* __restrict__ deg,
                                  float* __restrict__ inv_deg, int N) {
  int i = blockIdx.x * blockDim.x + threadIdx.x;  // over N*32 float4s
  if (i >= N * 32) return;
  int n = i >> 5;
  float inv = 1.0f / fmaxf(deg[n], 1.0f);
  float4 v = ((float4*)agg)[i];
  v.x *= inv; v.y *= inv; v.z *= inv; v.w *= inv;
  ((float4*)agg)[i] = v;
  if ((i & 31) == 0) inv_deg[n] = inv;
}

// C[n][j] = sum_{k<256} A(n,k)*W(j,k)  (+ epilogue)
// A(n,k) = k<128 ? A0[n*sa + k] : A1[n*sa + k-128]   (same for W with sw)
// EPI 0: C = relu(acc + bias[j])
// EPI 1: C = acc
// EPI 2: C = acc + bias[j] + inv_deg[n] * extra[n*sx + j]
// Tile: 64 rows x 64 cols, 256 threads, 4x4 micro-tile, K-chunk 16.
// LDS row stride 68 (+4 pad): transposed stores worst-case 2-way (free),
// b128 reads 16B-aligned (68*4B = 272B, 272%16==0).
template <int EPI>
__global__ __launch_bounds__(256, 4)
void gemm_k256(const float* __restrict__ A0, const float* __restrict__ A1, int sa,
               const float* __restrict__ W0, const float* __restrict__ W1, int sw,
               const float* __restrict__ bias,
               const float* __restrict__ inv_deg,
               const float* __restrict__ extra, int sx,
               float* __restrict__ C, int sc, int N) {
  __shared__ __align__(16) float As[16][68];
  __shared__ __align__(16) float Ws[16][68];
  const int t = threadIdx.x;
  const int n_blk = blockIdx.x * 64;
  const int j_blk = blockIdx.y * 64;
  const int tn = t & 15;        // micro-tile row group
  const int tj = t >> 4;        // micro-tile col group
  const int ln = t >> 2;        // loader: row/col 0..63
  const int lk = (t & 3) << 2;  // loader: k offset 0,4,8,12

  float acc[4][4] = {};

  for (int kc = 0; kc < 256; kc += 16) {
    const float* Ap = (kc < 128) ? A0 : A1;
    const float* Wp = (kc < 128) ? W0 : W1;
    const int koff = kc & 127;

    float4 av = make_float4(0.f, 0.f, 0.f, 0.f);
    const int gn = n_blk + ln;
    if (gn < N) av = *(const float4*)(Ap + (size_t)gn * sa + koff + lk);
    const float4 wv = *(const float4*)(Wp + (size_t)(j_blk + ln) * sw + koff + lk);

    __syncthreads();  // protect previous iteration's reads
    As[lk + 0][ln] = av.x; As[lk + 1][ln] = av.y;
    As[lk + 2][ln] = av.z; As[lk + 3][ln] = av.w;
    Ws[lk + 0][ln] = wv.x; Ws[lk + 1][ln] = wv.y;
    Ws[lk + 2][ln] = wv.z; Ws[lk + 3][ln] = wv.w;
    __syncthreads();

#pragma unroll
    for (int kk = 0; kk < 16; kk++) {
      const float4 a = *(const float4*)&As[kk][tn << 2];
      const float4 w = *(const float4*)&Ws[kk][tj << 2];
      acc[0][0] += a.x * w.x; acc[0][1] += a.x * w.y; acc[0][2] += a.x * w.z; acc[0][3] += a.x * w.w;
      acc[1][0] += a.y * w.x; acc[1][1] += a.y * w.y; acc[1][2] += a.y * w.z; acc[1][3] += a.y * w.w;
      acc[2][0] += a.z * w.x; acc[2][1] += a.z * w.y; acc[2][2] += a.z * w.z; acc[2][3] += a.z * w.w;
      acc[3][0] += a.w * w.x; acc[3][1] += a.w * w.y; acc[3][2] += a.w * w.z; acc[3][3] += a.w * w.w;
    }
  }

  const int j0 = j_blk + (tj << 2);
  float4 bv = make_float4(0.f, 0.f, 0.f, 0.f);
  if (EPI != 1) bv = *(const float4*)(bias + j0);

#pragma unroll
  for (int i = 0; i < 4; i++) {
    const int n = n_blk + (tn << 2) + i;
    if (n >= N) break;
    float4 r = make_float4(acc[i][0], acc[i][1], acc[i][2], acc[i][3]);
    if (EPI == 0) {
      r.x = fmaxf(r.x + bv.x, 0.f);
      r.y = fmaxf(r.y + bv.y, 0.f);
      r.z = fmaxf(r.z + bv.z, 0.f);
      r.w = fmaxf(r.w + bv.w, 0.f);
    } else if (EPI == 2) {
      const float idg = inv_deg[n];
      const float4 ev = *(const float4*)(extra + (size_t)n * sx + j0);
      r.x += bv.x + idg * ev.x;
      r.y += bv.y + idg * ev.y;
      r.z += bv.z + idg * ev.z;
      r.w += bv.w + idg * ev.w;
    }
    *(float4*)(C + (size_t)n * sc + j0) = r;
  }
}

extern "C" void kernel_launch(void* const* d_in, const int* in_sizes, int n_in,
                              void* d_out, int out_size, void* d_ws, size_t ws_size,
                              hipStream_t stream) {
  const float* x   = (const float*)d_in[0];
  const int*  eidx = (const int*)d_in[1];
  const float* W1l = (const float*)d_in[2];
  const float* b1l = (const float*)d_in[3];
  const float* W1r = (const float*)d_in[4];
  const float* W2l = (const float*)d_in[5];
  const float* b2l = (const float*)d_in[6];
  const float* W2r = (const float*)d_in[7];
  float* out = (float*)d_out;

  const int N = in_sizes[0] / 128;
  const int E = in_sizes[1] / 2;
  const int* src = eidx;
  const int* dst = eidx + E;

  float* ws_f = (float*)d_ws;
  // layout (floats): agg1[N*128] | deg[N] | inv[N] | h[N*256] | agg2[N*128]
  float* agg1 = ws_f;
  float* degb = agg1 + (size_t)N * 128;
  float* invd = degb + N;
  float* h    = invd + N;
  float* agg2 = h + (size_t)N * 256;
  float* tbuf = agg1;  // reuse agg1 after gemm1 consumes it

  // 1. zero
  const int n4a = (N * 128 + 2 * N) / 4;  // agg1+deg+inv contiguous
  zero4_kernel<<<(n4a + 255) / 256, 256, 0, stream>>>((float4*)agg1, n4a);
  const int n4b = N * 32;                 // agg2
  zero4_kernel<<<(n4b + 255) / 256, 256, 0, stream>>>((float4*)agg2, n4b);

  const int sblocks = (int)(((size_t)E * 32 + 255) / 256);

  // 2. scatter layer-1 input + degree
  scatter_kernel<<<sblocks, 256, 0, stream>>>(x, src, dst, agg1, degb, E);

  // 3. mean + inv_deg
  mean_scale_kernel<<<(N * 32 + 255) / 256, 256, 0, stream>>>(agg1, degb, invd, N);

  // 4. h = relu(mean1@W1l.T + x@W1r.T + b1l)
  dim3 g1((N + 63) / 64, 4);
  gemm_k256<0><<<g1, 256, 0, stream>>>(agg1, x, 128, W1l, W1r, 128, b1l,
                                       nullptr, nullptr, 0, h, 256, N);

  // 5. t = h@W2l.T
  dim3 g2((N + 63) / 64, 2);
  gemm_k256<1><<<g2, 256, 0, stream>>>(h, h + 128, 256, W2l, W2l + 128, 256,
                                       nullptr, nullptr, nullptr, 0, tbuf, 128, N);

  // 6. scatter layer-2 (post-transform: 128 floats/edge)
  scatter_kernel<<<sblocks, 256, 0, stream>>>(tbuf, src, dst, agg2, nullptr, E);

  // 7. out = inv_deg*agg2 + h@W2r.T + b2l
  gemm_k256<2><<<g2, 256, 0, stream>>>(h, h + 128, 256, W2r, W2r + 128, 256,
                                       b2l, invd, agg2, 128, out, 128, N);
}

// Round 2
// 534.275 us; speedup vs baseline: 5.6045x; 5.6045x over previous
//
#include <hip/hip_runtime.h>

// GraphSAGE 2-layer, fp32. N=50000, E=800000, D_IN=128, D_H=256, D_OUT=128.
//
// R2: replaced float-atomic scatter (2x1381us, atomic write-amplified) with
// CSR build (int atomics only) + per-node gather-mean (no atomics).
//
// Pipeline (all on `stream`):
//   1. zero cnt[N]
//   2. hist: cnt[dst]++                        (E int atomics)
//   3. scan: off[0..N] = exclusive_scan(cnt), cur = copy   (1 block, shfl scan)
//   4. fill: csr[cur[dst]++] = src             (E int atomics)
//   5. gather<false>: mean1[n] = mean_{s in adj(n)} x[s]
//   6. gemm EPI=0: h = relu(mean1@W1l.T + x@W1r.T + b1l)   [N,256]
//   7. gemm EPI=1: t = h@W2l.T                              [N,128] (t reuses mean1)
//   8. gemm EPI=2: out = h@W2r.T + b2l                      [N,128]
//   9. gather<true>:  out[n] += mean_{s in adj(n)} t[s]     (non-atomic RMW, node-owned)
//
// Layer-2 trick: mean(h[src])@W2l.T == mean((h@W2l.T)[src]) -> gather 128
// floats/edge instead of 256.

__global__ void zero_int_kernel(int* __restrict__ p, int n) {
  int i = blockIdx.x * blockDim.x + threadIdx.x;
  if (i < n) p[i] = 0;
}

__global__ void hist_kernel(const int* __restrict__ dst, int* __restrict__ cnt, int E) {
  int e = blockIdx.x * blockDim.x + threadIdx.x;
  if (e < E) atomicAdd(&cnt[dst[e]], 1);
}

// Single-workgroup exclusive scan over N values (shfl within waves, tiny LDS
// cross-wave combine, serial carry across 1024-chunks). N=50k -> ~49 chunks.
__global__ __launch_bounds__(1024) void scan_kernel(const int* __restrict__ cnt,
                                                    int* __restrict__ off,
                                                    int* __restrict__ cur,
                                                    int N, int E) {
  __shared__ int wsum[16];
  __shared__ int wincl[16];
  __shared__ int carryS;
  const int tid = threadIdx.x;
  const int lane = tid & 63;
  const int wv = tid >> 6;
  if (tid == 0) carryS = 0;
  __syncthreads();
  for (int base = 0; base < N; base += 1024) {
    const int carry = carryS;
    const int i = base + tid;
    const int v = (i < N) ? cnt[i] : 0;
    int s = v;  // inclusive scan within wave
#pragma unroll
    for (int o = 1; o < 64; o <<= 1) {
      int t = __shfl_up(s, o, 64);
      if (lane >= o) s += t;
    }
    if (lane == 63) wsum[wv] = s;
    __syncthreads();
    if (tid < 16) {
      int ws = wsum[tid];
#pragma unroll
      for (int o = 1; o < 16; o <<= 1) {
        int t = __shfl_up(ws, o, 16);
        if ((tid & 15) >= o) ws += t;
      }
      wincl[tid] = ws;
    }
    __syncthreads();
    const int wo = wv ? wincl[wv - 1] : 0;
    const int excl = carry + wo + s - v;
    if (i < N) { off[i] = excl; cur[i] = excl; }
    __syncthreads();
    if (tid == 1023) carryS = carry + wincl[15];
    __syncthreads();
  }
  if (tid == 0) off[N] = E;
}

__global__ void fill_kernel(const int* __restrict__ src, const int* __restrict__ dst,
                            int* __restrict__ cur, int* __restrict__ csr, int E) {
  int e = blockIdx.x * blockDim.x + threadIdx.x;
  if (e < E) {
    int p = atomicAdd(&cur[dst[e]], 1);
    csr[p] = src[e];
  }
}

// One 32-lane group per node; float4/lane (128 floats). 2-way unroll to keep
// two random loads in flight. ADD: accumulate into out (node-owned, no atomic).
template <bool ADD>
__global__ void gather_mean_kernel(const float* __restrict__ feat,
                                   const int* __restrict__ csr,
                                   const int* __restrict__ off,
                                   float* __restrict__ out, int N) {
  int tid = blockIdx.x * blockDim.x + threadIdx.x;
  int g = tid >> 5;
  if (g >= N) return;
  int lane = tid & 31;
  const int s0 = off[g], s1 = off[g + 1];
  float4 a0 = make_float4(0.f, 0.f, 0.f, 0.f);
  float4 a1 = make_float4(0.f, 0.f, 0.f, 0.f);
  int e = s0;
  for (; e + 1 < s1; e += 2) {
    int i0 = csr[e], i1 = csr[e + 1];
    float4 v0 = ((const float4*)(feat + (size_t)i0 * 128))[lane];
    float4 v1 = ((const float4*)(feat + (size_t)i1 * 128))[lane];
    a0.x += v0.x; a0.y += v0.y; a0.z += v0.z; a0.w += v0.w;
    a1.x += v1.x; a1.y += v1.y; a1.z += v1.z; a1.w += v1.w;
  }
  if (e < s1) {
    int i0 = csr[e];
    float4 v0 = ((const float4*)(feat + (size_t)i0 * 128))[lane];
    a0.x += v0.x; a0.y += v0.y; a0.z += v0.z; a0.w += v0.w;
  }
  const float inv = 1.0f / fmaxf((float)(s1 - s0), 1.0f);
  float4 r = make_float4((a0.x + a1.x) * inv, (a0.y + a1.y) * inv,
                         (a0.z + a1.z) * inv, (a0.w + a1.w) * inv);
  float4* o = (float4*)(out + (size_t)g * 128) + lane;
  if (ADD) {
    float4 c = *o;
    r.x += c.x; r.y += c.y; r.z += c.z; r.w += c.w;
  }
  *o = r;
}

// C[n][j] = sum_{k<256} A(n,k)*W(j,k)  (+ epilogue)
// A(n,k) = k<128 ? A0[n*sa + k] : A1[n*sa + k-128]   (same for W with sw)
// EPI 0: C = relu(acc + bias[j]);  EPI 1: C = acc;  EPI 2: C = acc + bias[j]
// Tile: 64 rows x 64 cols, 256 threads, 4x4 micro-tile, K-chunk 16.
// LDS row stride 68 (+4 pad): transposed stores worst-case 2-way (free),
// b128 reads 16B-aligned (68*4B = 272B, 272%16==0).
template <int EPI>
__global__ __launch_bounds__(256, 4)
void gemm_k256(const float* __restrict__ A0, const float* __restrict__ A1, int sa,
               const float* __restrict__ W0, const float* __restrict__ W1, int sw,
               const float* __restrict__ bias,
               float* __restrict__ C, int sc, int N) {
  __shared__ __align__(16) float As[16][68];
  __shared__ __align__(16) float Ws[16][68];
  const int t = threadIdx.x;
  const int n_blk = blockIdx.x * 64;
  const int j_blk = blockIdx.y * 64;
  const int tn = t & 15;        // micro-tile row group
  const int tj = t >> 4;        // micro-tile col group
  const int ln = t >> 2;        // loader: row/col 0..63
  const int lk = (t & 3) << 2;  // loader: k offset 0,4,8,12

  float acc[4][4] = {};

  for (int kc = 0; kc < 256; kc += 16) {
    const float* Ap = (kc < 128) ? A0 : A1;
    const float* Wp = (kc < 128) ? W0 : W1;
    const int koff = kc & 127;

    float4 av = make_float4(0.f, 0.f, 0.f, 0.f);
    const int gn = n_blk + ln;
    if (gn < N) av = *(const float4*)(Ap + (size_t)gn * sa + koff + lk);
    const float4 wv = *(const float4*)(Wp + (size_t)(j_blk + ln) * sw + koff + lk);

    __syncthreads();  // protect previous iteration's reads
    As[lk + 0][ln] = av.x; As[lk + 1][ln] = av.y;
    As[lk + 2][ln] = av.z; As[lk + 3][ln] = av.w;
    Ws[lk + 0][ln] = wv.x; Ws[lk + 1][ln] = wv.y;
    Ws[lk + 2][ln] = wv.z; Ws[lk + 3][ln] = wv.w;
    __syncthreads();

#pragma unroll
    for (int kk = 0; kk < 16; kk++) {
      const float4 a = *(const float4*)&As[kk][tn << 2];
      const float4 w = *(const float4*)&Ws[kk][tj << 2];
      acc[0][0] += a.x * w.x; acc[0][1] += a.x * w.y; acc[0][2] += a.x * w.z; acc[0][3] += a.x * w.w;
      acc[1][0] += a.y * w.x; acc[1][1] += a.y * w.y; acc[1][2] += a.y * w.z; acc[1][3] += a.y * w.w;
      acc[2][0] += a.z * w.x; acc[2][1] += a.z * w.y; acc[2][2] += a.z * w.z; acc[2][3] += a.z * w.w;
      acc[3][0] += a.w * w.x; acc[3][1] += a.w * w.y; acc[3][2] += a.w * w.z; acc[3][3] += a.w * w.w;
    }
  }

  const int j0 = j_blk + (tj << 2);
  float4 bv = make_float4(0.f, 0.f, 0.f, 0.f);
  if (EPI != 1) bv = *(const float4*)(bias + j0);

#pragma unroll
  for (int i = 0; i < 4; i++) {
    const int n = n_blk + (tn << 2) + i;
    if (n >= N) break;
    float4 r = make_float4(acc[i][0], acc[i][1], acc[i][2], acc[i][3]);
    if (EPI == 0) {
      r.x = fmaxf(r.x + bv.x, 0.f);
      r.y = fmaxf(r.y + bv.y, 0.f);
      r.z = fmaxf(r.z + bv.z, 0.f);
      r.w = fmaxf(r.w + bv.w, 0.f);
    } else if (EPI == 2) {
      r.x += bv.x; r.y += bv.y; r.z += bv.z; r.w += bv.w;
    }
    *(float4*)(C + (size_t)n * sc + j0) = r;
  }
}

extern "C" void kernel_launch(void* const* d_in, const int* in_sizes, int n_in,
                              void* d_out, int out_size, void* d_ws, size_t ws_size,
                              hipStream_t stream) {
  const float* x   = (const float*)d_in[0];
  const int*  eidx = (const int*)d_in[1];
  const float* W1l = (const float*)d_in[2];
  const float* b1l = (const float*)d_in[3];
  const float* W1r = (const float*)d_in[4];
  const float* W2l = (const float*)d_in[5];
  const float* b2l = (const float*)d_in[6];
  const float* W2r = (const float*)d_in[7];
  float* out = (float*)d_out;

  const int N = in_sizes[0] / 128;
  const int E = in_sizes[1] / 2;
  const int* src = eidx;
  const int* dst = eidx + E;

  // workspace layout: ints first, then floats
  int* cnt = (int*)d_ws;            // [N] histogram, reused as cursor
  int* off = cnt + N;               // [N+1]
  int* csr = off + N + 1;           // [E]
  float* mean1 = (float*)(csr + E + 1);  // [N*128], reused as t
  float* h     = mean1 + (size_t)N * 128; // [N*256]
  float* t     = mean1;

  // 1. zero histogram
  zero_int_kernel<<<(N + 255) / 256, 256, 0, stream>>>(cnt, N);
  // 2. histogram of dst
  hist_kernel<<<(E + 255) / 256, 256, 0, stream>>>(dst, cnt, E);
  // 3. exclusive scan -> off, cursor copy (cnt buffer reused as cursor)
  scan_kernel<<<1, 1024, 0, stream>>>(cnt, off, cnt, N, E);
  // 4. fill CSR adjacency
  fill_kernel<<<(E + 255) / 256, 256, 0, stream>>>(src, dst, cnt, csr, E);

  const int gblocks = (int)(((size_t)N * 32 + 255) / 256);
  // 5. mean1 = mean-aggregate(x)
  gather_mean_kernel<false><<<gblocks, 256, 0, stream>>>(x, csr, off, mean1, N);

  // 6. h = relu(mean1@W1l.T + x@W1r.T + b1l)
  dim3 g1((N + 63) / 64, 4);
  gemm_k256<0><<<g1, 256, 0, stream>>>(mean1, x, 128, W1l, W1r, 128, b1l, h, 256, N);

  // 7. t = h@W2l.T   (t aliases mean1; mean1 fully consumed by step 6)
  dim3 g2((N + 63) / 64, 2);
  gemm_k256<1><<<g2, 256, 0, stream>>>(h, h + 128, 256, W2l, W2l + 128, 256,
                                       nullptr, t, 128, N);

  // 8. out = h@W2r.T + b2l
  gemm_k256<2><<<g2, 256, 0, stream>>>(h, h + 128, 256, W2r, W2r + 128, 256,
                                       b2l, out, 128, N);

  // 9. out += mean-aggregate(t)
  gather_mean_kernel<true><<<gblocks, 256, 0, stream>>>(t, csr, off, out, N);
}

// Round 3
// 316.408 us; speedup vs baseline: 9.4636x; 1.6886x over previous
//
#include <hip/hip_runtime.h>

// GraphSAGE 2-layer. N=50000, E=800000, D_IN=128, D_H=256, D_OUT=128.
//
// R3: bf16 everywhere on the heavy paths.
//  - GEMMs: bf16 MFMA 16x16x32, fp32 accumulate. 128x128 tile, BK=64,
//    256 threads = 4 waves in 2x2, each wave 64x64 (4x4 MFMA frags).
//  - Gathers read bf16 features (half the random-read traffic).
//  - 3-phase multi-block scan replaces single-block serial scan.
//
// Pipeline:
//   wpack: W1l|W1r -> Wc1[256][256] bf16 ; W2l;W2r stacked -> Wc2[256][256]
//   xcvt:  x fp32 -> bf16 into A1 cols 128..255
//   zero cnt; hist; scan(3 phase); fill  -> CSR
//   gather1: A1 cols 0..127 = mean_{s in adj(n)} bf16(x[s])
//   gemm<0>: h = relu(A1 @ Wc1.T + b1l)            [N,256] bf16
//   gemm<1>: j_blk0: t = h@W2l.T (bf16) ; j_blk1: out = h@W2r.T + b2l (fp32)
//   gather2: out[n] += mean_{s in adj(n)} t[s]     (node-owned RMW)
//
// Layer-2 trick: mean(h[src])@W2l.T == mean((h@W2l.T)[src]).

typedef __attribute__((ext_vector_type(8))) short bf16x8;
typedef __attribute__((ext_vector_type(4))) float floatx4;

__device__ inline unsigned short f2b(float f) {
  unsigned int x = __float_as_uint(f);
  unsigned int r = (x + 0x7fffu + ((x >> 16) & 1u)) >> 16;
  return (unsigned short)r;
}

__global__ void wpack_kernel(const float* __restrict__ W1l, const float* __restrict__ W1r,
                             const float* __restrict__ W2l, const float* __restrict__ W2r,
                             unsigned short* __restrict__ Wc1, unsigned short* __restrict__ Wc2) {
  int i = blockIdx.x * blockDim.x + threadIdx.x;  // 0..65535
  int j = i >> 8, k = i & 255;
  float v1 = (k < 128) ? W1l[j * 128 + k] : W1r[j * 128 + (k - 128)];
  Wc1[i] = f2b(v1);
  float v2 = (j < 128) ? W2l[j * 256 + k] : W2r[(j - 128) * 256 + k];
  Wc2[i] = f2b(v2);
}

// x fp32 [N][128] -> bf16 into A1 cols 128..255 (row stride 256 bf16)
__global__ void xcvt_kernel(const float* __restrict__ x, unsigned short* __restrict__ A1, int N) {
  int i = blockIdx.x * blockDim.x + threadIdx.x;  // N*32, 4 elems each
  if (i >= N * 32) return;
  int n = i >> 5, c = (i & 31) * 4;
  float4 v = *(const float4*)(x + (size_t)n * 128 + c);
  uint2 p;
  p.x = (unsigned int)f2b(v.x) | ((unsigned int)f2b(v.y) << 16);
  p.y = (unsigned int)f2b(v.z) | ((unsigned int)f2b(v.w) << 16);
  *(uint2*)(A1 + (size_t)n * 256 + 128 + c) = p;
}

__global__ void zero_int_kernel(int* __restrict__ p, int n) {
  int i = blockIdx.x * blockDim.x + threadIdx.x;
  if (i < n) p[i] = 0;
}

__global__ void hist_kernel(const int* __restrict__ dst, int* __restrict__ cnt, int E) {
  int e = blockIdx.x * blockDim.x + threadIdx.x;
  if (e < E) atomicAdd(&cnt[dst[e]], 1);
}

// Phase A: per-1024-block exclusive scan; write block total to bsum[b].
__global__ __launch_bounds__(1024) void scan_blocks_kernel(const int* __restrict__ cnt,
                                                           int* __restrict__ off,
                                                           int* __restrict__ bsum, int N) {
  __shared__ int wsum[16];
  __shared__ int wincl[16];
  const int tid = threadIdx.x;
  const int lane = tid & 63;
  const int wv = tid >> 6;
  const int i = blockIdx.x * 1024 + tid;
  const int v = (i < N) ? cnt[i] : 0;
  int s = v;
#pragma unroll
  for (int o = 1; o < 64; o <<= 1) {
    int t = __shfl_up(s, o, 64);
    if (lane >= o) s += t;
  }
  if (lane == 63) wsum[wv] = s;
  __syncthreads();
  if (tid < 16) {
    int ws = wsum[tid];
#pragma unroll
    for (int o = 1; o < 16; o <<= 1) {
      int t = __shfl_up(ws, o, 16);
      if ((tid & 15) >= o) ws += t;
    }
    wincl[tid] = ws;
  }
  __syncthreads();
  const int wo = wv ? wincl[wv - 1] : 0;
  if (i < N) off[i] = wo + s - v;
  if (tid == 1023) bsum[blockIdx.x] = wo + s;
}

// Phase B: one wave scans <=64 block sums (exclusive, in place); off[N]=E.
__global__ void scan_sums_kernel(int* __restrict__ bsum, int* __restrict__ off, int B, int N, int E) {
  int lane = threadIdx.x;
  int v = (lane < B) ? bsum[lane] : 0;
  int s = v;
#pragma unroll
  for (int o = 1; o < 64; o <<= 1) {
    int t = __shfl_up(s, o, 64);
    if (lane >= o) s += t;
  }
  if (lane < B) bsum[lane] = s - v;
  if (lane == 0) off[N] = E;
}

// Phase C: add block offsets; also produce cursor copy.
__global__ __launch_bounds__(1024) void scan_add_kernel(int* __restrict__ off, int* __restrict__ cur,
                                                        const int* __restrict__ bsum, int N) {
  int i = blockIdx.x * 1024 + threadIdx.x;
  if (i < N) {
    int o = off[i] + bsum[blockIdx.x];
    off[i] = o;
    cur[i] = o;
  }
}

__global__ void fill_kernel(const int* __restrict__ src, const int* __restrict__ dst,
                            int* __restrict__ cur, int* __restrict__ csr, int E) {
  int e = blockIdx.x * blockDim.x + threadIdx.x;
  if (e < E) {
    int p = atomicAdd(&cur[dst[e]], 1);
    csr[p] = src[e];
  }
}

// mean-gather of bf16 features (row stride fs, in bf16 units), 32 lanes/node,
// uint2 (4 bf16) per lane. Write bf16 to ob (stride 256) at col 0..127.
__global__ void gather1_kernel(const unsigned short* __restrict__ feat,
                               const int* __restrict__ csr, const int* __restrict__ off,
                               unsigned short* __restrict__ ob, int N) {
  int tid = blockIdx.x * blockDim.x + threadIdx.x;
  int g = tid >> 5;
  if (g >= N) return;
  int lane = tid & 31;
  const int s0 = off[g], s1 = off[g + 1];
  float a0 = 0, a1 = 0, a2 = 0, a3 = 0, c0 = 0, c1 = 0, c2 = 0, c3 = 0;
  int e = s0;
  for (; e + 1 < s1; e += 2) {
    int i0 = csr[e], i1 = csr[e + 1];
    uint2 u = *(const uint2*)(feat + (size_t)i0 * 256 + lane * 4);
    uint2 w = *(const uint2*)(feat + (size_t)i1 * 256 + lane * 4);
    a0 += __uint_as_float(u.x << 16); a1 += __uint_as_float(u.x & 0xffff0000u);
    a2 += __uint_as_float(u.y << 16); a3 += __uint_as_float(u.y & 0xffff0000u);
    c0 += __uint_as_float(w.x << 16); c1 += __uint_as_float(w.x & 0xffff0000u);
    c2 += __uint_as_float(w.y << 16); c3 += __uint_as_float(w.y & 0xffff0000u);
  }
  if (e < s1) {
    int i0 = csr[e];
    uint2 u = *(const uint2*)(feat + (size_t)i0 * 256 + lane * 4);
    a0 += __uint_as_float(u.x << 16); a1 += __uint_as_float(u.x & 0xffff0000u);
    a2 += __uint_as_float(u.y << 16); a3 += __uint_as_float(u.y & 0xffff0000u);
  }
  const float inv = 1.0f / fmaxf((float)(s1 - s0), 1.0f);
  a0 = (a0 + c0) * inv; a1 = (a1 + c1) * inv; a2 = (a2 + c2) * inv; a3 = (a3 + c3) * inv;
  uint2 p;
  p.x = (unsigned int)f2b(a0) | ((unsigned int)f2b(a1) << 16);
  p.y = (unsigned int)f2b(a2) | ((unsigned int)f2b(a3) << 16);
  *(uint2*)(ob + (size_t)g * 256 + lane * 4) = p;
}

// mean-gather of bf16 t (stride 128); accumulate into fp32 out (stride 128).
__global__ void gather2_kernel(const unsigned short* __restrict__ t,
                               const int* __restrict__ csr, const int* __restrict__ off,
                               float* __restrict__ out, int N) {
  int tid = blockIdx.x * blockDim.x + threadIdx.x;
  int g = tid >> 5;
  if (g >= N) return;
  int lane = tid & 31;
  const int s0 = off[g], s1 = off[g + 1];
  float a0 = 0, a1 = 0, a2 = 0, a3 = 0, c0 = 0, c1 = 0, c2 = 0, c3 = 0;
  int e = s0;
  for (; e + 1 < s1; e += 2) {
    int i0 = csr[e], i1 = csr[e + 1];
    uint2 u = *(const uint2*)(t + (size_t)i0 * 128 + lane * 4);
    uint2 w = *(const uint2*)(t + (size_t)i1 * 128 + lane * 4);
    a0 += __uint_as_float(u.x << 16); a1 += __uint_as_float(u.x & 0xffff0000u);
    a2 += __uint_as_float(u.y << 16); a3 += __uint_as_float(u.y & 0xffff0000u);
    c0 += __uint_as_float(w.x << 16); c1 += __uint_as_float(w.x & 0xffff0000u);
    c2 += __uint_as_float(w.y << 16); c3 += __uint_as_float(w.y & 0xffff0000u);
  }
  if (e < s1) {
    int i0 = csr[e];
    uint2 u = *(const uint2*)(t + (size_t)i0 * 128 + lane * 4);
    a0 += __uint_as_float(u.x << 16); a1 += __uint_as_float(u.x & 0xffff0000u);
    a2 += __uint_as_float(u.y << 16); a3 += __uint_as_float(u.y & 0xffff0000u);
  }
  const float inv = 1.0f / fmaxf((float)(s1 - s0), 1.0f);
  float4* o = (float4*)(out + (size_t)g * 128) + lane;
  float4 c = *o;
  c.x += (a0 + c0) * inv; c.y += (a1 + c1) * inv;
  c.z += (a2 + c2) * inv; c.w += (a3 + c3) * inv;
  *o = c;
}

// bf16 MFMA GEMM: C[n][j] = sum_k A[n][k]*W[j][k], A [M][256], W [256][256].
// BM=128 BN=128 BK=64; 4 waves 2x2, each 64x64 = 4x4 mfma_f32_16x16x32_bf16.
// A-frag: lane holds A[m=lane&15][k=(lane>>4)*8+i]; B-frag: B[k][n=lane&15]
// = W[j=lane&15][k] -> same LDS read pattern for both.
// LDS stride 72 bf16 (144B): b128 reads worst-case 2-way (free); 16B aligned.
// MODE 0: Hout[n*256+j] = bf16(relu(acc + bias[j]))        (grid.y = 2)
// MODE 1: j_blk0: Hout[n*128+j] = bf16(acc)                 (t)
//         j_blk1: Fout[n*128+j] = acc + bias[j]             (out, fp32)
template <int MODE>
__global__ __launch_bounds__(256, 2)
void gemm_bf16(const unsigned short* __restrict__ A, const unsigned short* __restrict__ W,
               const float* __restrict__ bias, unsigned short* __restrict__ Hout,
               float* __restrict__ Fout, int M) {
  constexpr int LDA = 72;
  __shared__ __align__(16) unsigned short As[128 * LDA];
  __shared__ __align__(16) unsigned short Ws[128 * LDA];
  const int t = threadIdx.x;
  const int lane = t & 63;
  const int wave = t >> 6;
  const int wm = (wave & 1) * 64;
  const int wn = (wave >> 1) * 64;
  const int l15 = lane & 15;
  const int quad = lane >> 4;
  const int m_blk = blockIdx.x * 128;
  const int j_blk = blockIdx.y * 128;

  floatx4 acc[4][4] = {};

  for (int kc = 0; kc < 256; kc += 64) {
    __syncthreads();  // protect previous iteration's LDS reads
#pragma unroll
    for (int i = 0; i < 4; i++) {
      int c = t + 256 * i;          // 1024 chunks of 16B: 128 rows x 8
      int row = c >> 3;
      int col = (c & 7) * 8;
      int ar = m_blk + row;
      if (ar >= M) ar = M - 1;      // clamp (stores are guarded)
      uint4 av = *(const uint4*)(A + (size_t)ar * 256 + kc + col);
      *(uint4*)(As + row * LDA + col) = av;
      uint4 wv = *(const uint4*)(W + (size_t)(j_blk + row) * 256 + kc + col);
      *(uint4*)(Ws + row * LDA + col) = wv;
    }
    __syncthreads();
#pragma unroll
    for (int ks = 0; ks < 64; ks += 32) {
      bf16x8 af[4], bfr[4];
#pragma unroll
      for (int mt = 0; mt < 4; mt++)
        af[mt] = *(const bf16x8*)(As + (wm + mt * 16 + l15) * LDA + ks + quad * 8);
#pragma unroll
      for (int nt = 0; nt < 4; nt++)
        bfr[nt] = *(const bf16x8*)(Ws + (wn + nt * 16 + l15) * LDA + ks + quad * 8);
#pragma unroll
      for (int mt = 0; mt < 4; mt++)
#pragma unroll
        for (int nt = 0; nt < 4; nt++)
          acc[mt][nt] = __builtin_amdgcn_mfma_f32_16x16x32_bf16(af[mt], bfr[nt], acc[mt][nt], 0, 0, 0);
    }
  }

#pragma unroll
  for (int mt = 0; mt < 4; mt++) {
#pragma unroll
    for (int nt = 0; nt < 4; nt++) {
      const int jl = wn + nt * 16 + l15;  // 0..127 within block-col
      float bv = 0.f;
      if (MODE == 0) bv = bias[j_blk + jl];
      else if (j_blk != 0) bv = bias[jl];
#pragma unroll
      for (int r = 0; r < 4; r++) {
        const int node = m_blk + wm + mt * 16 + quad * 4 + r;
        if (node >= M) continue;
        const float v = acc[mt][nt][r];
        if (MODE == 0) {
          Hout[(size_t)node * 256 + j_blk + jl] = f2b(fmaxf(v + bv, 0.f));
        } else if (j_blk == 0) {
          Hout[(size_t)node * 128 + jl] = f2b(v);
        } else {
          Fout[(size_t)node * 128 + jl] = v + bv;
        }
      }
    }
  }
}

extern "C" void kernel_launch(void* const* d_in, const int* in_sizes, int n_in,
                              void* d_out, int out_size, void* d_ws, size_t ws_size,
                              hipStream_t stream) {
  const float* x   = (const float*)d_in[0];
  const int*  eidx = (const int*)d_in[1];
  const float* W1l = (const float*)d_in[2];
  const float* b1l = (const float*)d_in[3];
  const float* W1r = (const float*)d_in[4];
  const float* W2l = (const float*)d_in[5];
  const float* b2l = (const float*)d_in[6];
  const float* W2r = (const float*)d_in[7];
  float* out = (float*)d_out;

  const int N = in_sizes[0] / 128;
  const int E = in_sizes[1] / 2;
  const int* src = eidx;
  const int* dst = eidx + E;

  // workspace: ints, then bf16 regions (16B aligned)
  int* cnt  = (int*)d_ws;          // [N] histogram -> cursor
  int* off  = cnt + N;             // [N+1]
  int* bsum = off + N + 1;         // [64]
  int* csr  = bsum + 64;           // [E]
  size_t ioff = ((size_t)(N + N + 1 + 64 + E) * 4 + 15) & ~(size_t)15;
  unsigned short* A1  = (unsigned short*)((char*)d_ws + ioff);  // [N][256]
  unsigned short* h   = A1 + (size_t)N * 256;                   // [N][256]
  unsigned short* tb  = h + (size_t)N * 256;                    // [N][128]
  unsigned short* Wc1 = tb + (size_t)N * 128;                   // [256][256]
  unsigned short* Wc2 = Wc1 + 65536;                            // [256][256]

  const int SB = (N + 1023) / 1024;  // scan blocks (49)

  wpack_kernel<<<256, 256, 0, stream>>>(W1l, W1r, W2l, W2r, Wc1, Wc2);
  xcvt_kernel<<<(N * 32 + 255) / 256, 256, 0, stream>>>(x, A1, N);

  zero_int_kernel<<<(N + 255) / 256, 256, 0, stream>>>(cnt, N);
  hist_kernel<<<(E + 255) / 256, 256, 0, stream>>>(dst, cnt, E);
  scan_blocks_kernel<<<SB, 1024, 0, stream>>>(cnt, off, bsum, N);
  scan_sums_kernel<<<1, 64, 0, stream>>>(bsum, off, SB, N, E);
  scan_add_kernel<<<SB, 1024, 0, stream>>>(off, cnt, bsum, N);  // cnt = cursor
  fill_kernel<<<(E + 255) / 256, 256, 0, stream>>>(src, dst, cnt, csr, E);

  const int gblocks = (int)(((size_t)N * 32 + 255) / 256);
  // mean of bf16(x) -> A1 cols 0..127 (x bf16 lives at A1+128, stride 256)
  gather1_kernel<<<gblocks, 256, 0, stream>>>(A1 + 128, csr, off, A1, N);

  dim3 gg((N + 127) / 128, 2);
  // h = relu(A1 @ Wc1.T + b1l)
  gemm_bf16<0><<<gg, 256, 0, stream>>>(A1, Wc1, b1l, h, nullptr, N);
  // t = h@W2l.T (bf16) ; out = h@W2r.T + b2l (fp32)
  gemm_bf16<1><<<gg, 256, 0, stream>>>(h, Wc2, b2l, tb, out, N);
  // out += mean-aggregate(t)
  gather2_kernel<<<gblocks, 256, 0, stream>>>(tb, csr, off, out, N);
}

// Round 4
// 301.004 us; speedup vs baseline: 9.9479x; 1.0512x over previous
//
#include <hip/hip_runtime.h>

// GraphSAGE 2-layer. N=50000, E=800000, D_IN=128, D_H=256, D_OUT=128.
//
// R4: fill write-amp fix (4 dst-range passes keep live csr region L2-resident
// so same-line entries merge before eviction: WRITE 52MB -> ~20MB), wider
// gathers (16 lanes x uint4 = full 256B row per quarter-wave, 8 rows in
// flight), launch fusion (13 -> 9 kernels).
//
// Pipeline:
//   prep: Wc1/Wc2 bf16 pack | x->bf16 into A1 cols 128..255 | cnt=0 | off[N]=E
//   hist: cnt[dst]++
//   scan_blocks: per-1024 exclusive scan + block sums
//   scan_add: inline scan of 49 block sums + add; cursor copy
//   fill (4-pass): csr[cur[dst]++] = src
//   gather1: A1 cols 0..127 = mean_{s in adj(n)} bf16(x[s])
//   gemm<0>: h = relu(A1 @ Wc1.T + b1l)            [N,256] bf16
//   gemm<1>: j_blk0: t = h@W2l.T (bf16) ; j_blk1: out = h@W2r.T + b2l (fp32)
//   gather2: out[n] += mean_{s in adj(n)} t[s]     (node-owned RMW)
//
// Layer-2 trick: mean(h[src])@W2l.T == mean((h@W2l.T)[src]).

typedef __attribute__((ext_vector_type(8))) short bf16x8;
typedef __attribute__((ext_vector_type(4))) float floatx4;

__device__ inline unsigned short f2b(float f) {
  unsigned int x = __float_as_uint(f);
  unsigned int r = (x + 0x7fffu + ((x >> 16) & 1u)) >> 16;
  return (unsigned short)r;
}
__device__ inline float blo(unsigned int u) { return __uint_as_float(u << 16); }
__device__ inline float bhi(unsigned int u) { return __uint_as_float(u & 0xffff0000u); }

// Fused prep: weight pack, x->bf16 convert, cnt zero, off[N]=E.
__global__ void prep_kernel(const float* __restrict__ x,
                            const float* __restrict__ W1l, const float* __restrict__ W1r,
                            const float* __restrict__ W2l, const float* __restrict__ W2r,
                            unsigned short* __restrict__ Wc1, unsigned short* __restrict__ Wc2,
                            unsigned short* __restrict__ A1,
                            int* __restrict__ cnt, int* __restrict__ off, int N, int E) {
  int i = blockIdx.x * blockDim.x + threadIdx.x;
  if (i < 65536) {
    int j = i >> 8, k = i & 255;
    float v1 = (k < 128) ? W1l[j * 128 + k] : W1r[j * 128 + (k - 128)];
    Wc1[i] = f2b(v1);
    float v2 = (j < 128) ? W2l[j * 256 + k] : W2r[(j - 128) * 256 + k];
    Wc2[i] = f2b(v2);
  }
  if (i < N) cnt[i] = 0;
  if (i == 0) off[N] = E;
  if (i < N * 32) {
    int n = i >> 5, c = (i & 31) * 4;
    float4 v = *(const float4*)(x + (size_t)n * 128 + c);
    uint2 p;
    p.x = (unsigned int)f2b(v.x) | ((unsigned int)f2b(v.y) << 16);
    p.y = (unsigned int)f2b(v.z) | ((unsigned int)f2b(v.w) << 16);
    *(uint2*)(A1 + (size_t)n * 256 + 128 + c) = p;
  }
}

__global__ void hist_kernel(const int* __restrict__ dst, int* __restrict__ cnt, int E) {
  int e = blockIdx.x * blockDim.x + threadIdx.x;
  if (e < E) atomicAdd(&cnt[dst[e]], 1);
}

// Per-1024-block exclusive scan; block total -> bsum[b].
__global__ __launch_bounds__(1024) void scan_blocks_kernel(const int* __restrict__ cnt,
                                                           int* __restrict__ off,
                                                           int* __restrict__ bsum, int N) {
  __shared__ int wsum[16];
  __shared__ int wincl[16];
  const int tid = threadIdx.x;
  const int lane = tid & 63;
  const int wv = tid >> 6;
  const int i = blockIdx.x * 1024 + tid;
  const int v = (i < N) ? cnt[i] : 0;
  int s = v;
#pragma unroll
  for (int o = 1; o < 64; o <<= 1) {
    int t = __shfl_up(s, o, 64);
    if (lane >= o) s += t;
  }
  if (lane == 63) wsum[wv] = s;
  __syncthreads();
  if (tid < 16) {
    int ws = wsum[tid];
#pragma unroll
    for (int o = 1; o < 16; o <<= 1) {
      int t = __shfl_up(ws, o, 16);
      if ((tid & 15) >= o) ws += t;
    }
    wincl[tid] = ws;
  }
  __syncthreads();
  const int wo = wv ? wincl[wv - 1] : 0;
  if (i < N) off[i] = wo + s - v;
  if (tid == 1023) bsum[blockIdx.x] = wo + s;
}

// Add block offsets (block-sum scan inlined: <=64 sums, wave 0); cursor copy.
__global__ __launch_bounds__(1024) void scan_add_kernel(int* __restrict__ off, int* __restrict__ cur,
                                                        const int* __restrict__ bsum, int N, int SB) {
  __shared__ int bofs[64];
  const int tid = threadIdx.x;
  if (tid < 64) {
    int v = (tid < SB) ? bsum[tid] : 0;
    int s = v;
#pragma unroll
    for (int o = 1; o < 64; o <<= 1) {
      int t = __shfl_up(s, o, 64);
      if (tid >= o) s += t;
    }
    bofs[tid] = s - v;
  }
  __syncthreads();
  int i = blockIdx.x * 1024 + tid;
  if (i < N) {
    int o = off[i] + bofs[blockIdx.x];
    off[i] = o;
    cur[i] = o;
  }
}

// 4-pass fill: pass p only handles dst>>14 == p, so the live csr region
// (<=1MB) stays L2-resident and same-line writes merge before eviction.
__global__ void fill_kernel(const int* __restrict__ src, const int* __restrict__ dst,
                            int* __restrict__ cur, int* __restrict__ csr, int E, int chunks) {
  int pass = blockIdx.x / chunks;
  int c = blockIdx.x - pass * chunks;
  int e = c * 256 + threadIdx.x;
  if (e >= E) return;
  int d = dst[e];
  if ((d >> 14) != pass) return;
  int p = atomicAdd(&cur[d], 1);
  csr[p] = src[e];
}

// Gather-mean, one 64-lane wave per node: 16 lanes x uint4 (8 bf16) = one
// full 256B row per quarter-wave, 4 edges in flight + 2-edge unroll.
// feat row stride 256 ushorts; output bf16 at ob[g*256 + col] (cols 0..127).
__global__ void gather1_kernel(const unsigned short* __restrict__ feat,
                               const int* __restrict__ csr, const int* __restrict__ off,
                               unsigned short* __restrict__ ob, int N) {
  int wid = (blockIdx.x * blockDim.x + threadIdx.x) >> 6;
  if (wid >= N) return;
  const int lane = threadIdx.x & 63;
  const int sub = lane >> 4;
  const int col8 = (lane & 15) * 8;
  const int s0 = off[wid], s1 = off[wid + 1];
  float a[8] = {};
  int e = s0 + sub;
  for (; e + 4 < s1; e += 8) {
    int i0 = csr[e], i1 = csr[e + 4];
    uint4 u = *(const uint4*)(feat + (size_t)i0 * 256 + col8);
    uint4 w = *(const uint4*)(feat + (size_t)i1 * 256 + col8);
    a[0] += blo(u.x); a[1] += bhi(u.x); a[2] += blo(u.y); a[3] += bhi(u.y);
    a[4] += blo(u.z); a[5] += bhi(u.z); a[6] += blo(u.w); a[7] += bhi(u.w);
    a[0] += blo(w.x); a[1] += bhi(w.x); a[2] += blo(w.y); a[3] += bhi(w.y);
    a[4] += blo(w.z); a[5] += bhi(w.z); a[6] += blo(w.w); a[7] += bhi(w.w);
  }
  if (e < s1) {
    int i0 = csr[e];
    uint4 u = *(const uint4*)(feat + (size_t)i0 * 256 + col8);
    a[0] += blo(u.x); a[1] += bhi(u.x); a[2] += blo(u.y); a[3] += bhi(u.y);
    a[4] += blo(u.z); a[5] += bhi(u.z); a[6] += blo(u.w); a[7] += bhi(u.w);
  }
#pragma unroll
  for (int k = 0; k < 8; k++) {
    a[k] += __shfl_xor(a[k], 16, 64);
    a[k] += __shfl_xor(a[k], 32, 64);
  }
  if (sub == 0) {
    const float inv = 1.0f / fmaxf((float)(s1 - s0), 1.0f);
    uint4 p;
    p.x = (unsigned int)f2b(a[0] * inv) | ((unsigned int)f2b(a[1] * inv) << 16);
    p.y = (unsigned int)f2b(a[2] * inv) | ((unsigned int)f2b(a[3] * inv) << 16);
    p.z = (unsigned int)f2b(a[4] * inv) | ((unsigned int)f2b(a[5] * inv) << 16);
    p.w = (unsigned int)f2b(a[6] * inv) | ((unsigned int)f2b(a[7] * inv) << 16);
    *(uint4*)(ob + (size_t)wid * 256 + col8) = p;
  }
}

// Same structure; feat (t) stride 128 ushorts; accumulate into fp32 out.
__global__ void gather2_kernel(const unsigned short* __restrict__ t,
                               const int* __restrict__ csr, const int* __restrict__ off,
                               float* __restrict__ out, int N) {
  int wid = (blockIdx.x * blockDim.x + threadIdx.x) >> 6;
  if (wid >= N) return;
  const int lane = threadIdx.x & 63;
  const int sub = lane >> 4;
  const int col8 = (lane & 15) * 8;
  const int s0 = off[wid], s1 = off[wid + 1];
  float a[8] = {};
  int e = s0 + sub;
  for (; e + 4 < s1; e += 8) {
    int i0 = csr[e], i1 = csr[e + 4];
    uint4 u = *(const uint4*)(t + (size_t)i0 * 128 + col8);
    uint4 w = *(const uint4*)(t + (size_t)i1 * 128 + col8);
    a[0] += blo(u.x); a[1] += bhi(u.x); a[2] += blo(u.y); a[3] += bhi(u.y);
    a[4] += blo(u.z); a[5] += bhi(u.z); a[6] += blo(u.w); a[7] += bhi(u.w);
    a[0] += blo(w.x); a[1] += bhi(w.x); a[2] += blo(w.y); a[3] += bhi(w.y);
    a[4] += blo(w.z); a[5] += bhi(w.z); a[6] += blo(w.w); a[7] += bhi(w.w);
  }
  if (e < s1) {
    int i0 = csr[e];
    uint4 u = *(const uint4*)(t + (size_t)i0 * 128 + col8);
    a[0] += blo(u.x); a[1] += bhi(u.x); a[2] += blo(u.y); a[3] += bhi(u.y);
    a[4] += blo(u.z); a[5] += bhi(u.z); a[6] += blo(u.w); a[7] += bhi(u.w);
  }
#pragma unroll
  for (int k = 0; k < 8; k++) {
    a[k] += __shfl_xor(a[k], 16, 64);
    a[k] += __shfl_xor(a[k], 32, 64);
  }
  if (sub == 0) {
    const float inv = 1.0f / fmaxf((float)(s1 - s0), 1.0f);
    float4* o = (float4*)(out + (size_t)wid * 128 + col8);
    float4 c0 = o[0], c1 = o[1];
    c0.x += a[0] * inv; c0.y += a[1] * inv; c0.z += a[2] * inv; c0.w += a[3] * inv;
    c1.x += a[4] * inv; c1.y += a[5] * inv; c1.z += a[6] * inv; c1.w += a[7] * inv;
    o[0] = c0; o[1] = c1;
  }
}

// bf16 MFMA GEMM: C[n][j] = sum_k A[n][k]*W[j][k], A [M][256], W [256][256].
// BM=128 BN=128 BK=64; 4 waves 2x2, each 64x64 = 4x4 mfma_f32_16x16x32_bf16.
// LDS stride 72 bf16 (144B): b128 reads worst-case 2-way (free); 16B aligned.
// MODE 0: Hout[n*256+j] = bf16(relu(acc + bias[j]))        (grid.y = 2)
// MODE 1: j_blk0: Hout[n*128+j] = bf16(acc)                 (t)
//         j_blk1: Fout[n*128+j] = acc + bias[j]             (out, fp32)
template <int MODE>
__global__ __launch_bounds__(256, 2)
void gemm_bf16(const unsigned short* __restrict__ A, const unsigned short* __restrict__ W,
               const float* __restrict__ bias, unsigned short* __restrict__ Hout,
               float* __restrict__ Fout, int M) {
  constexpr int LDA = 72;
  __shared__ __align__(16) unsigned short As[128 * LDA];
  __shared__ __align__(16) unsigned short Ws[128 * LDA];
  const int t = threadIdx.x;
  const int lane = t & 63;
  const int wave = t >> 6;
  const int wm = (wave & 1) * 64;
  const int wn = (wave >> 1) * 64;
  const int l15 = lane & 15;
  const int quad = lane >> 4;
  const int m_blk = blockIdx.x * 128;
  const int j_blk = blockIdx.y * 128;

  floatx4 acc[4][4] = {};

  for (int kc = 0; kc < 256; kc += 64) {
    __syncthreads();
#pragma unroll
    for (int i = 0; i < 4; i++) {
      int c = t + 256 * i;
      int row = c >> 3;
      int col = (c & 7) * 8;
      int ar = m_blk + row;
      if (ar >= M) ar = M - 1;
      uint4 av = *(const uint4*)(A + (size_t)ar * 256 + kc + col);
      *(uint4*)(As + row * LDA + col) = av;
      uint4 wv = *(const uint4*)(W + (size_t)(j_blk + row) * 256 + kc + col);
      *(uint4*)(Ws + row * LDA + col) = wv;
    }
    __syncthreads();
#pragma unroll
    for (int ks = 0; ks < 64; ks += 32) {
      bf16x8 af[4], bfr[4];
#pragma unroll
      for (int mt = 0; mt < 4; mt++)
        af[mt] = *(const bf16x8*)(As + (wm + mt * 16 + l15) * LDA + ks + quad * 8);
#pragma unroll
      for (int nt = 0; nt < 4; nt++)
        bfr[nt] = *(const bf16x8*)(Ws + (wn + nt * 16 + l15) * LDA + ks + quad * 8);
#pragma unroll
      for (int mt = 0; mt < 4; mt++)
#pragma unroll
        for (int nt = 0; nt < 4; nt++)
          acc[mt][nt] = __builtin_amdgcn_mfma_f32_16x16x32_bf16(af[mt], bfr[nt], acc[mt][nt], 0, 0, 0);
    }
  }

#pragma unroll
  for (int mt = 0; mt < 4; mt++) {
#pragma unroll
    for (int nt = 0; nt < 4; nt++) {
      const int jl = wn + nt * 16 + l15;
      float bv = 0.f;
      if (MODE == 0) bv = bias[j_blk + jl];
      else if (j_blk != 0) bv = bias[jl];
#pragma unroll
      for (int r = 0; r < 4; r++) {
        const int node = m_blk + wm + mt * 16 + quad * 4 + r;
        if (node >= M) continue;
        const float v = acc[mt][nt][r];
        if (MODE == 0) {
          Hout[(size_t)node * 256 + j_blk + jl] = f2b(fmaxf(v + bv, 0.f));
        } else if (j_blk == 0) {
          Hout[(size_t)node * 128 + jl] = f2b(v);
        } else {
          Fout[(size_t)node * 128 + jl] = v + bv;
        }
      }
    }
  }
}

extern "C" void kernel_launch(void* const* d_in, const int* in_sizes, int n_in,
                              void* d_out, int out_size, void* d_ws, size_t ws_size,
                              hipStream_t stream) {
  const float* x   = (const float*)d_in[0];
  const int*  eidx = (const int*)d_in[1];
  const float* W1l = (const float*)d_in[2];
  const float* b1l = (const float*)d_in[3];
  const float* W1r = (const float*)d_in[4];
  const float* W2l = (const float*)d_in[5];
  const float* b2l = (const float*)d_in[6];
  const float* W2r = (const float*)d_in[7];
  float* out = (float*)d_out;

  const int N = in_sizes[0] / 128;
  const int E = in_sizes[1] / 2;
  const int* src = eidx;
  const int* dst = eidx + E;

  int* cnt  = (int*)d_ws;          // [N] histogram -> cursor
  int* off  = cnt + N;             // [N+1]
  int* bsum = off + N + 1;         // [64]
  int* csr  = bsum + 64;           // [E]
  size_t ioff = ((size_t)(N + N + 1 + 64 + E) * 4 + 15) & ~(size_t)15;
  unsigned short* A1  = (unsigned short*)((char*)d_ws + ioff);  // [N][256]
  unsigned short* h   = A1 + (size_t)N * 256;                   // [N][256]
  unsigned short* tb  = h + (size_t)N * 256;                    // [N][128]
  unsigned short* Wc1 = tb + (size_t)N * 128;                   // [256][256]
  unsigned short* Wc2 = Wc1 + 65536;                            // [256][256]

  const int SB = (N + 1023) / 1024;  // 49

  prep_kernel<<<(N * 32 + 255) / 256, 256, 0, stream>>>(x, W1l, W1r, W2l, W2r,
                                                        Wc1, Wc2, A1, cnt, off, N, E);
  hist_kernel<<<(E + 255) / 256, 256, 0, stream>>>(dst, cnt, E);
  scan_blocks_kernel<<<SB, 1024, 0, stream>>>(cnt, off, bsum, N);
  scan_add_kernel<<<SB, 1024, 0, stream>>>(off, cnt, bsum, N, SB);  // cnt = cursor

  const int chunks = (E + 255) / 256;
  fill_kernel<<<chunks * 4, 256, 0, stream>>>(src, dst, cnt, csr, E, chunks);

  const int gblocks = (N + 3) / 4;  // 1 wave (64 lanes) per node
  gather1_kernel<<<gblocks, 256, 0, stream>>>(A1 + 128, csr, off, A1, N);

  dim3 gg((N + 127) / 128, 2);
  gemm_bf16<0><<<gg, 256, 0, stream>>>(A1, Wc1, b1l, h, nullptr, N);
  gemm_bf16<1><<<gg, 256, 0, stream>>>(h, Wc2, b2l, tb, out, N);
  gather2_kernel<<<gblocks, 256, 0, stream>>>(tb, csr, off, out, N);
}

// Round 5
// 298.138 us; speedup vs baseline: 10.0436x; 1.0096x over previous
//
#include <hip/hip_runtime.h>

// GraphSAGE 2-layer. N=50000, E=800000, D_IN=128, D_H=256, D_OUT=128.
//
// R5: XCD-affinity fill (grp = blockIdx&7 -> XCD via round-robin dispatch;
// each group owns a dst range so each csr 64B line is dirtied by exactly ONE
// XCD's L2 and merges before writeback -- R4 showed cross-XCD false sharing,
// not capacity, caused the 13x write amplification). Gathers unrolled to 4
// edges in flight per quarter-wave.
//
// Pipeline:
//   prep: Wc1/Wc2 bf16 pack | x->bf16 into A1 cols 128..255 | cnt=0 | off[N]=E
//   hist: cnt[dst]++
//   scan_blocks / scan_add: exclusive scan -> off, cursor copy
//   fill (8 XCD groups): csr[cur[dst]++] = src
//   gather1: A1 cols 0..127 = mean_{s in adj(n)} bf16(x[s])
//   gemm<0>: h = relu(A1 @ Wc1.T + b1l)            [N,256] bf16
//   gemm<1>: j_blk0: t = h@W2l.T (bf16) ; j_blk1: out = h@W2r.T + b2l (fp32)
//   gather2: out[n] += mean_{s in adj(n)} t[s]     (node-owned RMW)
//
// Layer-2 trick: mean(h[src])@W2l.T == mean((h@W2l.T)[src]).

typedef __attribute__((ext_vector_type(8))) short bf16x8;
typedef __attribute__((ext_vector_type(4))) float floatx4;

__device__ inline unsigned short f2b(float f) {
  unsigned int x = __float_as_uint(f);
  unsigned int r = (x + 0x7fffu + ((x >> 16) & 1u)) >> 16;
  return (unsigned short)r;
}
__device__ inline float blo(unsigned int u) { return __uint_as_float(u << 16); }
__device__ inline float bhi(unsigned int u) { return __uint_as_float(u & 0xffff0000u); }

// Fused prep: weight pack, x->bf16 convert, cnt zero, off[N]=E.
__global__ void prep_kernel(const float* __restrict__ x,
                            const float* __restrict__ W1l, const float* __restrict__ W1r,
                            const float* __restrict__ W2l, const float* __restrict__ W2r,
                            unsigned short* __restrict__ Wc1, unsigned short* __restrict__ Wc2,
                            unsigned short* __restrict__ A1,
                            int* __restrict__ cnt, int* __restrict__ off, int N, int E) {
  int i = blockIdx.x * blockDim.x + threadIdx.x;
  if (i < 65536) {
    int j = i >> 8, k = i & 255;
    float v1 = (k < 128) ? W1l[j * 128 + k] : W1r[j * 128 + (k - 128)];
    Wc1[i] = f2b(v1);
    float v2 = (j < 128) ? W2l[j * 256 + k] : W2r[(j - 128) * 256 + k];
    Wc2[i] = f2b(v2);
  }
  if (i < N) cnt[i] = 0;
  if (i == 0) off[N] = E;
  if (i < N * 32) {
    int n = i >> 5, c = (i & 31) * 4;
    float4 v = *(const float4*)(x + (size_t)n * 128 + c);
    uint2 p;
    p.x = (unsigned int)f2b(v.x) | ((unsigned int)f2b(v.y) << 16);
    p.y = (unsigned int)f2b(v.z) | ((unsigned int)f2b(v.w) << 16);
    *(uint2*)(A1 + (size_t)n * 256 + 128 + c) = p;
  }
}

__global__ void hist_kernel(const int* __restrict__ dst, int* __restrict__ cnt, int E) {
  int e = blockIdx.x * blockDim.x + threadIdx.x;
  if (e < E) atomicAdd(&cnt[dst[e]], 1);
}

// Per-1024-block exclusive scan; block total -> bsum[b].
__global__ __launch_bounds__(1024) void scan_blocks_kernel(const int* __restrict__ cnt,
                                                           int* __restrict__ off,
                                                           int* __restrict__ bsum, int N) {
  __shared__ int wsum[16];
  __shared__ int wincl[16];
  const int tid = threadIdx.x;
  const int lane = tid & 63;
  const int wv = tid >> 6;
  const int i = blockIdx.x * 1024 + tid;
  const int v = (i < N) ? cnt[i] : 0;
  int s = v;
#pragma unroll
  for (int o = 1; o < 64; o <<= 1) {
    int t = __shfl_up(s, o, 64);
    if (lane >= o) s += t;
  }
  if (lane == 63) wsum[wv] = s;
  __syncthreads();
  if (tid < 16) {
    int ws = wsum[tid];
#pragma unroll
    for (int o = 1; o < 16; o <<= 1) {
      int t = __shfl_up(ws, o, 16);
      if ((tid & 15) >= o) ws += t;
    }
    wincl[tid] = ws;
  }
  __syncthreads();
  const int wo = wv ? wincl[wv - 1] : 0;
  if (i < N) off[i] = wo + s - v;
  if (tid == 1023) bsum[blockIdx.x] = wo + s;
}

// Add block offsets (block-sum scan inlined: <=64 sums, wave 0); cursor copy.
__global__ __launch_bounds__(1024) void scan_add_kernel(int* __restrict__ off, int* __restrict__ cur,
                                                        const int* __restrict__ bsum, int N, int SB) {
  __shared__ int bofs[64];
  const int tid = threadIdx.x;
  if (tid < 64) {
    int v = (tid < SB) ? bsum[tid] : 0;
    int s = v;
#pragma unroll
    for (int o = 1; o < 64; o <<= 1) {
      int t = __shfl_up(s, o, 64);
      if (tid >= o) s += t;
    }
    bofs[tid] = s - v;
  }
  __syncthreads();
  int i = blockIdx.x * 1024 + tid;
  if (i < N) {
    int o = off[i] + bofs[blockIdx.x];
    off[i] = o;
    cur[i] = o;
  }
}

// XCD-affinity fill: grp = blockIdx&7 maps to one XCD (round-robin dispatch).
// Group g handles only dst in [g*R, (g+1)*R): every csr line is written by a
// single XCD, so partial lines merge in its L2 before one writeback.
__global__ void fill_kernel(const int* __restrict__ src, const int* __restrict__ dst,
                            int* __restrict__ cur, int* __restrict__ csr, int E, int R) {
  const int grp = blockIdx.x & 7;
  const int e = (blockIdx.x >> 3) * 256 + threadIdx.x;
  if (e >= E) return;
  const int d = dst[e];
  if ((unsigned)(d - grp * R) >= (unsigned)R) return;
  const int p = atomicAdd(&cur[d], 1);
  csr[p] = src[e];
}

// Gather-mean, one 64-lane wave per node: quarter-wave (16 lanes x uint4) per
// edge slot, 4 slots/wave, 4 edges in flight per slot (batched index loads).
// feat row stride 256 ushorts; output bf16 at ob[g*256 + col] (cols 0..127).
__global__ void gather1_kernel(const unsigned short* __restrict__ feat,
                               const int* __restrict__ csr, const int* __restrict__ off,
                               unsigned short* __restrict__ ob, int N) {
  int wid = (blockIdx.x * blockDim.x + threadIdx.x) >> 6;
  if (wid >= N) return;
  const int lane = threadIdx.x & 63;
  const int sub = lane >> 4;
  const int col8 = (lane & 15) * 8;
  const int s0 = off[wid], s1 = off[wid + 1];
  float a[8] = {};
  int e = s0 + sub;
  for (; e + 12 < s1; e += 16) {
    int i0 = csr[e], i1 = csr[e + 4], i2 = csr[e + 8], i3 = csr[e + 12];
    uint4 u0 = *(const uint4*)(feat + (size_t)i0 * 256 + col8);
    uint4 u1 = *(const uint4*)(feat + (size_t)i1 * 256 + col8);
    uint4 u2 = *(const uint4*)(feat + (size_t)i2 * 256 + col8);
    uint4 u3 = *(const uint4*)(feat + (size_t)i3 * 256 + col8);
    a[0] += blo(u0.x); a[1] += bhi(u0.x); a[2] += blo(u0.y); a[3] += bhi(u0.y);
    a[4] += blo(u0.z); a[5] += bhi(u0.z); a[6] += blo(u0.w); a[7] += bhi(u0.w);
    a[0] += blo(u1.x); a[1] += bhi(u1.x); a[2] += blo(u1.y); a[3] += bhi(u1.y);
    a[4] += blo(u1.z); a[5] += bhi(u1.z); a[6] += blo(u1.w); a[7] += bhi(u1.w);
    a[0] += blo(u2.x); a[1] += bhi(u2.x); a[2] += blo(u2.y); a[3] += bhi(u2.y);
    a[4] += blo(u2.z); a[5] += bhi(u2.z); a[6] += blo(u2.w); a[7] += bhi(u2.w);
    a[0] += blo(u3.x); a[1] += bhi(u3.x); a[2] += blo(u3.y); a[3] += bhi(u3.y);
    a[4] += blo(u3.z); a[5] += bhi(u3.z); a[6] += blo(u3.w); a[7] += bhi(u3.w);
  }
  for (; e < s1; e += 4) {
    int i0 = csr[e];
    uint4 u = *(const uint4*)(feat + (size_t)i0 * 256 + col8);
    a[0] += blo(u.x); a[1] += bhi(u.x); a[2] += blo(u.y); a[3] += bhi(u.y);
    a[4] += blo(u.z); a[5] += bhi(u.z); a[6] += blo(u.w); a[7] += bhi(u.w);
  }
#pragma unroll
  for (int k = 0; k < 8; k++) {
    a[k] += __shfl_xor(a[k], 16, 64);
    a[k] += __shfl_xor(a[k], 32, 64);
  }
  if (sub == 0) {
    const float inv = 1.0f / fmaxf((float)(s1 - s0), 1.0f);
    uint4 p;
    p.x = (unsigned int)f2b(a[0] * inv) | ((unsigned int)f2b(a[1] * inv) << 16);
    p.y = (unsigned int)f2b(a[2] * inv) | ((unsigned int)f2b(a[3] * inv) << 16);
    p.z = (unsigned int)f2b(a[4] * inv) | ((unsigned int)f2b(a[5] * inv) << 16);
    p.w = (unsigned int)f2b(a[6] * inv) | ((unsigned int)f2b(a[7] * inv) << 16);
    *(uint4*)(ob + (size_t)wid * 256 + col8) = p;
  }
}

// Same structure; feat (t) stride 128 ushorts; accumulate into fp32 out.
__global__ void gather2_kernel(const unsigned short* __restrict__ t,
                               const int* __restrict__ csr, const int* __restrict__ off,
                               float* __restrict__ out, int N) {
  int wid = (blockIdx.x * blockDim.x + threadIdx.x) >> 6;
  if (wid >= N) return;
  const int lane = threadIdx.x & 63;
  const int sub = lane >> 4;
  const int col8 = (lane & 15) * 8;
  const int s0 = off[wid], s1 = off[wid + 1];
  float a[8] = {};
  int e = s0 + sub;
  for (; e + 12 < s1; e += 16) {
    int i0 = csr[e], i1 = csr[e + 4], i2 = csr[e + 8], i3 = csr[e + 12];
    uint4 u0 = *(const uint4*)(t + (size_t)i0 * 128 + col8);
    uint4 u1 = *(const uint4*)(t + (size_t)i1 * 128 + col8);
    uint4 u2 = *(const uint4*)(t + (size_t)i2 * 128 + col8);
    uint4 u3 = *(const uint4*)(t + (size_t)i3 * 128 + col8);
    a[0] += blo(u0.x); a[1] += bhi(u0.x); a[2] += blo(u0.y); a[3] += bhi(u0.y);
    a[4] += blo(u0.z); a[5] += bhi(u0.z); a[6] += blo(u0.w); a[7] += bhi(u0.w);
    a[0] += blo(u1.x); a[1] += bhi(u1.x); a[2] += blo(u1.y); a[3] += bhi(u1.y);
    a[4] += blo(u1.z); a[5] += bhi(u1.z); a[6] += blo(u1.w); a[7] += bhi(u1.w);
    a[0] += blo(u2.x); a[1] += bhi(u2.x); a[2] += blo(u2.y); a[3] += bhi(u2.y);
    a[4] += blo(u2.z); a[5] += bhi(u2.z); a[6] += blo(u2.w); a[7] += bhi(u2.w);
    a[0] += blo(u3.x); a[1] += bhi(u3.x); a[2] += blo(u3.y); a[3] += bhi(u3.y);
    a[4] += blo(u3.z); a[5] += bhi(u3.z); a[6] += blo(u3.w); a[7] += bhi(u3.w);
  }
  for (; e < s1; e += 4) {
    int i0 = csr[e];
    uint4 u = *(const uint4*)(t + (size_t)i0 * 128 + col8);
    a[0] += blo(u.x); a[1] += bhi(u.x); a[2] += blo(u.y); a[3] += bhi(u.y);
    a[4] += blo(u.z); a[5] += bhi(u.z); a[6] += blo(u.w); a[7] += bhi(u.w);
  }
#pragma unroll
  for (int k = 0; k < 8; k++) {
    a[k] += __shfl_xor(a[k], 16, 64);
    a[k] += __shfl_xor(a[k], 32, 64);
  }
  if (sub == 0) {
    const float inv = 1.0f / fmaxf((float)(s1 - s0), 1.0f);
    float4* o = (float4*)(out + (size_t)wid * 128 + col8);
    float4 c0 = o[0], c1 = o[1];
    c0.x += a[0] * inv; c0.y += a[1] * inv; c0.z += a[2] * inv; c0.w += a[3] * inv;
    c1.x += a[4] * inv; c1.y += a[5] * inv; c1.z += a[6] * inv; c1.w += a[7] * inv;
    o[0] = c0; o[1] = c1;
  }
}

// bf16 MFMA GEMM: C[n][j] = sum_k A[n][k]*W[j][k], A [M][256], W [256][256].
// BM=128 BN=128 BK=64; 4 waves 2x2, each 64x64 = 4x4 mfma_f32_16x16x32_bf16.
// LDS stride 72 bf16 (144B): b128 reads worst-case 2-way (free); 16B aligned.
// MODE 0: Hout[n*256+j] = bf16(relu(acc + bias[j]))        (grid.y = 2)
// MODE 1: j_blk0: Hout[n*128+j] = bf16(acc)                 (t)
//         j_blk1: Fout[n*128+j] = acc + bias[j]             (out, fp32)
template <int MODE>
__global__ __launch_bounds__(256, 2)
void gemm_bf16(const unsigned short* __restrict__ A, const unsigned short* __restrict__ W,
               const float* __restrict__ bias, unsigned short* __restrict__ Hout,
               float* __restrict__ Fout, int M) {
  constexpr int LDA = 72;
  __shared__ __align__(16) unsigned short As[128 * LDA];
  __shared__ __align__(16) unsigned short Ws[128 * LDA];
  const int t = threadIdx.x;
  const int lane = t & 63;
  const int wave = t >> 6;
  const int wm = (wave & 1) * 64;
  const int wn = (wave >> 1) * 64;
  const int l15 = lane & 15;
  const int quad = lane >> 4;
  const int m_blk = blockIdx.x * 128;
  const int j_blk = blockIdx.y * 128;

  floatx4 acc[4][4] = {};

  for (int kc = 0; kc < 256; kc += 64) {
    __syncthreads();
#pragma unroll
    for (int i = 0; i < 4; i++) {
      int c = t + 256 * i;
      int row = c >> 3;
      int col = (c & 7) * 8;
      int ar = m_blk + row;
      if (ar >= M) ar = M - 1;
      uint4 av = *(const uint4*)(A + (size_t)ar * 256 + kc + col);
      *(uint4*)(As + row * LDA + col) = av;
      uint4 wv = *(const uint4*)(W + (size_t)(j_blk + row) * 256 + kc + col);
      *(uint4*)(Ws + row * LDA + col) = wv;
    }
    __syncthreads();
#pragma unroll
    for (int ks = 0; ks < 64; ks += 32) {
      bf16x8 af[4], bfr[4];
#pragma unroll
      for (int mt = 0; mt < 4; mt++)
        af[mt] = *(const bf16x8*)(As + (wm + mt * 16 + l15) * LDA + ks + quad * 8);
#pragma unroll
      for (int nt = 0; nt < 4; nt++)
        bfr[nt] = *(const bf16x8*)(Ws + (wn + nt * 16 + l15) * LDA + ks + quad * 8);
#pragma unroll
      for (int mt = 0; mt < 4; mt++)
#pragma unroll
        for (int nt = 0; nt < 4; nt++)
          acc[mt][nt] = __builtin_amdgcn_mfma_f32_16x16x32_bf16(af[mt], bfr[nt], acc[mt][nt], 0, 0, 0);
    }
  }

#pragma unroll
  for (int mt = 0; mt < 4; mt++) {
#pragma unroll
    for (int nt = 0; nt < 4; nt++) {
      const int jl = wn + nt * 16 + l15;
      float bv = 0.f;
      if (MODE == 0) bv = bias[j_blk + jl];
      else if (j_blk != 0) bv = bias[jl];
#pragma unroll
      for (int r = 0; r < 4; r++) {
        const int node = m_blk + wm + mt * 16 + quad * 4 + r;
        if (node >= M) continue;
        const float v = acc[mt][nt][r];
        if (MODE == 0) {
          Hout[(size_t)node * 256 + j_blk + jl] = f2b(fmaxf(v + bv, 0.f));
        } else if (j_blk == 0) {
          Hout[(size_t)node * 128 + jl] = f2b(v);
        } else {
          Fout[(size_t)node * 128 + jl] = v + bv;
        }
      }
    }
  }
}

extern "C" void kernel_launch(void* const* d_in, const int* in_sizes, int n_in,
                              void* d_out, int out_size, void* d_ws, size_t ws_size,
                              hipStream_t stream) {
  const float* x   = (const float*)d_in[0];
  const int*  eidx = (const int*)d_in[1];
  const float* W1l = (const float*)d_in[2];
  const float* b1l = (const float*)d_in[3];
  const float* W1r = (const float*)d_in[4];
  const float* W2l = (const float*)d_in[5];
  const float* b2l = (const float*)d_in[6];
  const float* W2r = (const float*)d_in[7];
  float* out = (float*)d_out;

  const int N = in_sizes[0] / 128;
  const int E = in_sizes[1] / 2;
  const int* src = eidx;
  const int* dst = eidx + E;

  int* cnt  = (int*)d_ws;          // [N] histogram -> cursor
  int* off  = cnt + N;             // [N+1]
  int* bsum = off + N + 1;         // [64]
  int* csr  = bsum + 64;           // [E]
  size_t ioff = ((size_t)(N + N + 1 + 64 + E) * 4 + 15) & ~(size_t)15;
  unsigned short* A1  = (unsigned short*)((char*)d_ws + ioff);  // [N][256]
  unsigned short* h   = A1 + (size_t)N * 256;                   // [N][256]
  unsigned short* tb  = h + (size_t)N * 256;                    // [N][128]
  unsigned short* Wc1 = tb + (size_t)N * 128;                   // [256][256]
  unsigned short* Wc2 = Wc1 + 65536;                            // [256][256]

  const int SB = (N + 1023) / 1024;  // 49

  prep_kernel<<<(N * 32 + 255) / 256, 256, 0, stream>>>(x, W1l, W1r, W2l, W2r,
                                                        Wc1, Wc2, A1, cnt, off, N, E);
  hist_kernel<<<(E + 255) / 256, 256, 0, stream>>>(dst, cnt, E);
  scan_blocks_kernel<<<SB, 1024, 0, stream>>>(cnt, off, bsum, N);
  scan_add_kernel<<<SB, 1024, 0, stream>>>(off, cnt, bsum, N, SB);  // cnt = cursor

  const int chunks = (E + 255) / 256;
  const int R = (N + 7) / 8;  // dst range per XCD group
  fill_kernel<<<chunks * 8, 256, 0, stream>>>(src, dst, cnt, csr, E, R);

  const int gblocks = (N + 3) / 4;  // 1 wave (64 lanes) per node
  gather1_kernel<<<gblocks, 256, 0, stream>>>(A1 + 128, csr, off, A1, N);

  dim3 gg((N + 127) / 128, 2);
  gemm_bf16<0><<<gg, 256, 0, stream>>>(A1, Wc1, b1l, h, nullptr, N);
  gemm_bf16<1><<<gg, 256, 0, stream>>>(h, Wc2, b2l, tb, out, N);
  gather2_kernel<<<gblocks, 256, 0, stream>>>(tb, csr, off, out, N);
}

// Round 6
// 274.082 us; speedup vs baseline: 10.9251x; 1.0878x over previous
//
#include <hip/hip_runtime.h>

// GraphSAGE 2-layer. N=50000, E=800000, D_IN=128, D_H=256, D_OUT=128.
//
// R6: atomic-free fill. hist records each edge's rank (atomicAdd return) as a
// coalesced side-array; fill becomes a plain scattered store (no RMW chain).
// Gathers restructured to 8 slots x 8 lanes (2 uint4 half-row loads/edge):
// same bytes, ~2x fewer VMEM+address instructions.
//
// Pipeline:
//   prep: Wc1/Wc2 bf16 pack | x->bf16 into A1 cols 128..255 | cnt=0 | off[N]=E
//   hist: rank[e] = cnt[dst[e]]++            (E int atomics, rank coalesced)
//   scan_blocks / scan_add: exclusive scan -> off
//   fill: csr[off[dst[e]] + rank[e]] = src[e]   (plain stores, 4 edges/thread)
//   gather1: A1 cols 0..127 = mean_{s in adj(n)} bf16(x[s])
//   gemm<0>: h = relu(A1 @ Wc1.T + b1l)            [N,256] bf16
//   gemm<1>: j_blk0: t = h@W2l.T (bf16) ; j_blk1: out = h@W2r.T + b2l (fp32)
//   gather2: out[n] += mean_{s in adj(n)} t[s]     (node-owned RMW)
//
// Layer-2 trick: mean(h[src])@W2l.T == mean((h@W2l.T)[src]).

typedef __attribute__((ext_vector_type(8))) short bf16x8;
typedef __attribute__((ext_vector_type(4))) float floatx4;

__device__ inline unsigned short f2b(float f) {
  unsigned int x = __float_as_uint(f);
  unsigned int r = (x + 0x7fffu + ((x >> 16) & 1u)) >> 16;
  return (unsigned short)r;
}
__device__ inline float blo(unsigned int u) { return __uint_as_float(u << 16); }
__device__ inline float bhi(unsigned int u) { return __uint_as_float(u & 0xffff0000u); }

#define ACC8(A, u)                                            \
  {                                                           \
    A[0] += blo((u).x); A[1] += bhi((u).x);                   \
    A[2] += blo((u).y); A[3] += bhi((u).y);                   \
    A[4] += blo((u).z); A[5] += bhi((u).z);                   \
    A[6] += blo((u).w); A[7] += bhi((u).w);                   \
  }

// Fused prep: weight pack, x->bf16 convert, cnt zero, off[N]=E.
__global__ void prep_kernel(const float* __restrict__ x,
                            const float* __restrict__ W1l, const float* __restrict__ W1r,
                            const float* __restrict__ W2l, const float* __restrict__ W2r,
                            unsigned short* __restrict__ Wc1, unsigned short* __restrict__ Wc2,
                            unsigned short* __restrict__ A1,
                            int* __restrict__ cnt, int* __restrict__ off, int N, int E) {
  int i = blockIdx.x * blockDim.x + threadIdx.x;
  if (i < 65536) {
    int j = i >> 8, k = i & 255;
    float v1 = (k < 128) ? W1l[j * 128 + k] : W1r[j * 128 + (k - 128)];
    Wc1[i] = f2b(v1);
    float v2 = (j < 128) ? W2l[j * 256 + k] : W2r[(j - 128) * 256 + k];
    Wc2[i] = f2b(v2);
  }
  if (i < N) cnt[i] = 0;
  if (i == 0) off[N] = E;
  if (i < N * 32) {
    int n = i >> 5, c = (i & 31) * 4;
    float4 v = *(const float4*)(x + (size_t)n * 128 + c);
    uint2 p;
    p.x = (unsigned int)f2b(v.x) | ((unsigned int)f2b(v.y) << 16);
    p.y = (unsigned int)f2b(v.z) | ((unsigned int)f2b(v.w) << 16);
    *(uint2*)(A1 + (size_t)n * 256 + 128 + c) = p;
  }
}

// Histogram + per-edge rank capture (4 edges/thread, vectorized loads).
__global__ void hist_kernel(const int* __restrict__ dst, int* __restrict__ cnt,
                            int* __restrict__ rank, int E) {
  int i = blockIdx.x * blockDim.x + threadIdx.x;
  int e = i * 4;
  if (e + 3 < E) {
    int4 d = *(const int4*)(dst + e);
    int4 r;
    r.x = atomicAdd(&cnt[d.x], 1);
    r.y = atomicAdd(&cnt[d.y], 1);
    r.z = atomicAdd(&cnt[d.z], 1);
    r.w = atomicAdd(&cnt[d.w], 1);
    *(int4*)(rank + e) = r;
  } else {
    for (; e < E; e++) rank[e] = atomicAdd(&cnt[dst[e]], 1);
  }
}

// Per-1024-block exclusive scan; block total -> bsum[b].
__global__ __launch_bounds__(1024) void scan_blocks_kernel(const int* __restrict__ cnt,
                                                           int* __restrict__ off,
                                                           int* __restrict__ bsum, int N) {
  __shared__ int wsum[16];
  __shared__ int wincl[16];
  const int tid = threadIdx.x;
  const int lane = tid & 63;
  const int wv = tid >> 6;
  const int i = blockIdx.x * 1024 + tid;
  const int v = (i < N) ? cnt[i] : 0;
  int s = v;
#pragma unroll
  for (int o = 1; o < 64; o <<= 1) {
    int t = __shfl_up(s, o, 64);
    if (lane >= o) s += t;
  }
  if (lane == 63) wsum[wv] = s;
  __syncthreads();
  if (tid < 16) {
    int ws = wsum[tid];
#pragma unroll
    for (int o = 1; o < 16; o <<= 1) {
      int t = __shfl_up(ws, o, 16);
      if ((tid & 15) >= o) ws += t;
    }
    wincl[tid] = ws;
  }
  __syncthreads();
  const int wo = wv ? wincl[wv - 1] : 0;
  if (i < N) off[i] = wo + s - v;
  if (tid == 1023) bsum[blockIdx.x] = wo + s;
}

// Add block offsets (block-sum scan inlined: <=64 sums, wave 0).
__global__ __launch_bounds__(1024) void scan_add_kernel(int* __restrict__ off,
                                                        const int* __restrict__ bsum, int N, int SB) {
  __shared__ int bofs[64];
  const int tid = threadIdx.x;
  if (tid < 64) {
    int v = (tid < SB) ? bsum[tid] : 0;
    int s = v;
#pragma unroll
    for (int o = 1; o < 64; o <<= 1) {
      int t = __shfl_up(s, o, 64);
      if (tid >= o) s += t;
    }
    bofs[tid] = s - v;
  }
  __syncthreads();
  int i = blockIdx.x * 1024 + tid;
  if (i < N) off[i] = off[i] + bofs[blockIdx.x];
}

// Atomic-free fill: plain scattered stores, 4 edges/thread.
__global__ void fill_kernel(const int* __restrict__ src, const int* __restrict__ dst,
                            const int* __restrict__ rank, const int* __restrict__ off,
                            int* __restrict__ csr, int E) {
  int i = blockIdx.x * blockDim.x + threadIdx.x;
  int e = i * 4;
  if (e + 3 < E) {
    int4 d = *(const int4*)(dst + e);
    int4 r = *(const int4*)(rank + e);
    int4 s = *(const int4*)(src + e);
    csr[off[d.x] + r.x] = s.x;
    csr[off[d.y] + r.y] = s.y;
    csr[off[d.z] + r.z] = s.z;
    csr[off[d.w] + r.w] = s.w;
  } else {
    for (; e < E; e++) csr[off[dst[e]] + rank[e]] = src[e];
  }
}

// Gather-mean, one 64-lane wave per node. 8 slots x 8 lanes; each slot loads
// one edge's 256B row as 2 x uint4 half-rows; 2-edge unroll -> 16 edges per
// iteration with only 4 row-load instructions.
// feat row stride 256 ushorts; output bf16 at ob[g*256 + col] (cols 0..127).
__global__ void gather1_kernel(const unsigned short* __restrict__ feat,
                               const int* __restrict__ csr, const int* __restrict__ off,
                               unsigned short* __restrict__ ob, int N) {
  int wid = (blockIdx.x * blockDim.x + threadIdx.x) >> 6;
  if (wid >= N) return;
  const int lane = threadIdx.x & 63;
  const int slot = lane >> 3;
  const int j = lane & 7;
  const int c0 = j * 8;  // bf16 col base within half-row
  const int s0 = off[wid], s1 = off[wid + 1];
  float a[16] = {};
  int e = s0 + slot;
  for (; e + 8 < s1; e += 16) {
    int i0 = csr[e], i1 = csr[e + 8];
    uint4 u0 = *(const uint4*)(feat + (size_t)i0 * 256 + c0);
    uint4 v0 = *(const uint4*)(feat + (size_t)i0 * 256 + 64 + c0);
    uint4 u1 = *(const uint4*)(feat + (size_t)i1 * 256 + c0);
    uint4 v1 = *(const uint4*)(feat + (size_t)i1 * 256 + 64 + c0);
    ACC8(a, u0); ACC8((a + 8), v0);
    ACC8(a, u1); ACC8((a + 8), v1);
  }
  for (; e < s1; e += 8) {
    int i0 = csr[e];
    uint4 u0 = *(const uint4*)(feat + (size_t)i0 * 256 + c0);
    uint4 v0 = *(const uint4*)(feat + (size_t)i0 * 256 + 64 + c0);
    ACC8(a, u0); ACC8((a + 8), v0);
  }
#pragma unroll
  for (int k = 0; k < 16; k++) {
    a[k] += __shfl_xor(a[k], 8, 64);
    a[k] += __shfl_xor(a[k], 16, 64);
    a[k] += __shfl_xor(a[k], 32, 64);
  }
  if (slot == 0) {
    const float inv = 1.0f / fmaxf((float)(s1 - s0), 1.0f);
    uint4 p;
    p.x = (unsigned int)f2b(a[0] * inv) | ((unsigned int)f2b(a[1] * inv) << 16);
    p.y = (unsigned int)f2b(a[2] * inv) | ((unsigned int)f2b(a[3] * inv) << 16);
    p.z = (unsigned int)f2b(a[4] * inv) | ((unsigned int)f2b(a[5] * inv) << 16);
    p.w = (unsigned int)f2b(a[6] * inv) | ((unsigned int)f2b(a[7] * inv) << 16);
    *(uint4*)(ob + (size_t)wid * 256 + c0) = p;
    p.x = (unsigned int)f2b(a[8] * inv) | ((unsigned int)f2b(a[9] * inv) << 16);
    p.y = (unsigned int)f2b(a[10] * inv) | ((unsigned int)f2b(a[11] * inv) << 16);
    p.z = (unsigned int)f2b(a[12] * inv) | ((unsigned int)f2b(a[13] * inv) << 16);
    p.w = (unsigned int)f2b(a[14] * inv) | ((unsigned int)f2b(a[15] * inv) << 16);
    *(uint4*)(ob + (size_t)wid * 256 + 64 + c0) = p;
  }
}

// Same structure; feat (t) stride 128 ushorts; accumulate into fp32 out.
__global__ void gather2_kernel(const unsigned short* __restrict__ t,
                               const int* __restrict__ csr, const int* __restrict__ off,
                               float* __restrict__ out, int N) {
  int wid = (blockIdx.x * blockDim.x + threadIdx.x) >> 6;
  if (wid >= N) return;
  const int lane = threadIdx.x & 63;
  const int slot = lane >> 3;
  const int j = lane & 7;
  const int c0 = j * 8;
  const int s0 = off[wid], s1 = off[wid + 1];
  float a[16] = {};
  int e = s0 + slot;
  for (; e + 8 < s1; e += 16) {
    int i0 = csr[e], i1 = csr[e + 8];
    uint4 u0 = *(const uint4*)(t + (size_t)i0 * 128 + c0);
    uint4 v0 = *(const uint4*)(t + (size_t)i0 * 128 + 64 + c0);
    uint4 u1 = *(const uint4*)(t + (size_t)i1 * 128 + c0);
    uint4 v1 = *(const uint4*)(t + (size_t)i1 * 128 + 64 + c0);
    ACC8(a, u0); ACC8((a + 8), v0);
    ACC8(a, u1); ACC8((a + 8), v1);
  }
  for (; e < s1; e += 8) {
    int i0 = csr[e];
    uint4 u0 = *(const uint4*)(t + (size_t)i0 * 128 + c0);
    uint4 v0 = *(const uint4*)(t + (size_t)i0 * 128 + 64 + c0);
    ACC8(a, u0); ACC8((a + 8), v0);
  }
#pragma unroll
  for (int k = 0; k < 16; k++) {
    a[k] += __shfl_xor(a[k], 8, 64);
    a[k] += __shfl_xor(a[k], 16, 64);
    a[k] += __shfl_xor(a[k], 32, 64);
  }
  if (slot == 0) {
    const float inv = 1.0f / fmaxf((float)(s1 - s0), 1.0f);
    float4* o0 = (float4*)(out + (size_t)wid * 128 + c0);
    float4* o1 = (float4*)(out + (size_t)wid * 128 + 64 + c0);
    float4 r0 = o0[0], r1 = o0[1], r2 = o1[0], r3 = o1[1];
    r0.x += a[0] * inv;  r0.y += a[1] * inv;  r0.z += a[2] * inv;  r0.w += a[3] * inv;
    r1.x += a[4] * inv;  r1.y += a[5] * inv;  r1.z += a[6] * inv;  r1.w += a[7] * inv;
    r2.x += a[8] * inv;  r2.y += a[9] * inv;  r2.z += a[10] * inv; r2.w += a[11] * inv;
    r3.x += a[12] * inv; r3.y += a[13] * inv; r3.z += a[14] * inv; r3.w += a[15] * inv;
    o0[0] = r0; o0[1] = r1; o1[0] = r2; o1[1] = r3;
  }
}

// bf16 MFMA GEMM: C[n][j] = sum_k A[n][k]*W[j][k], A [M][256], W [256][256].
// BM=128 BN=128 BK=64; 4 waves 2x2, each 64x64 = 4x4 mfma_f32_16x16x32_bf16.
// LDS stride 72 bf16 (144B): b128 reads worst-case 2-way (free); 16B aligned.
// MODE 0: Hout[n*256+j] = bf16(relu(acc + bias[j]))        (grid.y = 2)
// MODE 1: j_blk0: Hout[n*128+j] = bf16(acc)                 (t)
//         j_blk1: Fout[n*128+j] = acc + bias[j]             (out, fp32)
template <int MODE>
__global__ __launch_bounds__(256, 2)
void gemm_bf16(const unsigned short* __restrict__ A, const unsigned short* __restrict__ W,
               const float* __restrict__ bias, unsigned short* __restrict__ Hout,
               float* __restrict__ Fout, int M) {
  constexpr int LDA = 72;
  __shared__ __align__(16) unsigned short As[128 * LDA];
  __shared__ __align__(16) unsigned short Ws[128 * LDA];
  const int t = threadIdx.x;
  const int lane = t & 63;
  const int wave = t >> 6;
  const int wm = (wave & 1) * 64;
  const int wn = (wave >> 1) * 64;
  const int l15 = lane & 15;
  const int quad = lane >> 4;
  const int m_blk = blockIdx.x * 128;
  const int j_blk = blockIdx.y * 128;

  floatx4 acc[4][4] = {};

  for (int kc = 0; kc < 256; kc += 64) {
    __syncthreads();
#pragma unroll
    for (int i = 0; i < 4; i++) {
      int c = t + 256 * i;
      int row = c >> 3;
      int col = (c & 7) * 8;
      int ar = m_blk + row;
      if (ar >= M) ar = M - 1;
      uint4 av = *(const uint4*)(A + (size_t)ar * 256 + kc + col);
      *(uint4*)(As + row * LDA + col) = av;
      uint4 wv = *(const uint4*)(W + (size_t)(j_blk + row) * 256 + kc + col);
      *(uint4*)(Ws + row * LDA + col) = wv;
    }
    __syncthreads();
#pragma unroll
    for (int ks = 0; ks < 64; ks += 32) {
      bf16x8 af[4], bfr[4];
#pragma unroll
      for (int mt = 0; mt < 4; mt++)
        af[mt] = *(const bf16x8*)(As + (wm + mt * 16 + l15) * LDA + ks + quad * 8);
#pragma unroll
      for (int nt = 0; nt < 4; nt++)
        bfr[nt] = *(const bf16x8*)(Ws + (wn + nt * 16 + l15) * LDA + ks + quad * 8);
#pragma unroll
      for (int mt = 0; mt < 4; mt++)
#pragma unroll
        for (int nt = 0; nt < 4; nt++)
          acc[mt][nt] = __builtin_amdgcn_mfma_f32_16x16x32_bf16(af[mt], bfr[nt], acc[mt][nt], 0, 0, 0);
    }
  }

#pragma unroll
  for (int mt = 0; mt < 4; mt++) {
#pragma unroll
    for (int nt = 0; nt < 4; nt++) {
      const int jl = wn + nt * 16 + l15;
      float bv = 0.f;
      if (MODE == 0) bv = bias[j_blk + jl];
      else if (j_blk != 0) bv = bias[jl];
#pragma unroll
      for (int r = 0; r < 4; r++) {
        const int node = m_blk + wm + mt * 16 + quad * 4 + r;
        if (node >= M) continue;
        const float v = acc[mt][nt][r];
        if (MODE == 0) {
          Hout[(size_t)node * 256 + j_blk + jl] = f2b(fmaxf(v + bv, 0.f));
        } else if (j_blk == 0) {
          Hout[(size_t)node * 128 + jl] = f2b(v);
        } else {
          Fout[(size_t)node * 128 + jl] = v + bv;
        }
      }
    }
  }
}

extern "C" void kernel_launch(void* const* d_in, const int* in_sizes, int n_in,
                              void* d_out, int out_size, void* d_ws, size_t ws_size,
                              hipStream_t stream) {
  const float* x   = (const float*)d_in[0];
  const int*  eidx = (const int*)d_in[1];
  const float* W1l = (const float*)d_in[2];
  const float* b1l = (const float*)d_in[3];
  const float* W1r = (const float*)d_in[4];
  const float* W2l = (const float*)d_in[5];
  const float* b2l = (const float*)d_in[6];
  const float* W2r = (const float*)d_in[7];
  float* out = (float*)d_out;

  const int N = in_sizes[0] / 128;
  const int E = in_sizes[1] / 2;
  const int* src = eidx;
  const int* dst = eidx + E;

  int* cnt  = (int*)d_ws;          // [N]
  int* off  = cnt + N;             // [N+1]
  int* bsum = off + N + 1;         // [64]
  int* rank = bsum + 64;           // [E]
  int* csr  = rank + E;            // [E]
  size_t ioff = ((size_t)(N + N + 1 + 64 + 2 * E) * 4 + 15) & ~(size_t)15;
  unsigned short* A1  = (unsigned short*)((char*)d_ws + ioff);  // [N][256]
  unsigned short* h   = A1 + (size_t)N * 256;                   // [N][256]
  unsigned short* tb  = h + (size_t)N * 256;                    // [N][128]
  unsigned short* Wc1 = tb + (size_t)N * 128;                   // [256][256]
  unsigned short* Wc2 = Wc1 + 65536;                            // [256][256]

  const int SB = (N + 1023) / 1024;  // 49

  prep_kernel<<<(N * 32 + 255) / 256, 256, 0, stream>>>(x, W1l, W1r, W2l, W2r,
                                                        Wc1, Wc2, A1, cnt, off, N, E);
  hist_kernel<<<(E / 4 + 255) / 256, 256, 0, stream>>>(dst, cnt, rank, E);
  scan_blocks_kernel<<<SB, 1024, 0, stream>>>(cnt, off, bsum, N);
  scan_add_kernel<<<SB, 1024, 0, stream>>>(off, bsum, N, SB);
  fill_kernel<<<(E / 4 + 255) / 256, 256, 0, stream>>>(src, dst, rank, off, csr, E);

  const int gblocks = (N + 3) / 4;  // 1 wave (64 lanes) per node
  gather1_kernel<<<gblocks, 256, 0, stream>>>(A1 + 128, csr, off, A1, N);

  dim3 gg((N + 127) / 128, 2);
  gemm_bf16<0><<<gg, 256, 0, stream>>>(A1, Wc1, b1l, h, nullptr, N);
  gemm_bf16<1><<<gg, 256, 0, stream>>>(h, Wc2, b2l, tb, out, N);
  gather2_kernel<<<gblocks, 256, 0, stream>>>(tb, csr, off, out, N);
}